// Round 9
// baseline (4689.883 us; speedup 1.0000x reference)
//
#include <hip/hip_runtime.h>

// ---------------------------------------------------------------------------
// SpikeRNN — r9: same exact-numpy-f32 numerics as passing r7/r8.
// rnn_kernel restructured: 512 threads x 2 consecutive columns/thread,
// float2 gather loads, ballot+bit-interleave mask build, one-step-ahead
// inff/noise prefetch. Ascending serial f32 add chains preserved bit-exactly.
// ---------------------------------------------------------------------------

constexpr int NB_IN  = 256;
constexpr int NB_REC = 1024;
constexpr int NB_OUT = 64;
constexpr int BATCH  = 128;
constexpr int NB_STEPS = 300;
constexpr int TSTEPS = NB_STEPS - 1;

constexpr float ALPHA_F = (float)0.8187307530779818;  // f32(exp(-0.2))
constexpr float BETA_F  = (float)0.9048374180359595;  // f32(exp(-0.1))

// d_out element offsets (f32 elements)
constexpr size_t OUT_REC_OFF = 0;
constexpr size_t SPK_REC_OFF = (size_t)BATCH * NB_STEPS * NB_OUT;
constexpr size_t WRECD_OFF   = SPK_REC_OFF + (size_t)BATCH * NB_STEPS * NB_REC;
constexpr size_t WOUTD_OFF   = WRECD_OFF + (size_t)NB_REC * NB_REC;
constexpr size_t WFF_OFF     = WOUTD_OFF + (size_t)NB_REC * NB_OUT;
constexpr int    OUT_TOTAL   = 43155456;

constexpr int SZ_INPUTS = BATCH * NB_STEPS * NB_IN;   // 9,830,400
constexpr int SZ_NOISE  = BATCH * NB_STEPS * NB_REC;  // 39,321,600
constexpr int SZ_WFF    = NB_IN * NB_REC;             // 262,144
constexpr int SZ_WREC   = NB_REC * NB_REC;            // 1,048,576
constexpr int SZ_WOUT   = NB_REC * NB_OUT;            // 65,536
constexpr int SZ_DSIGN  = NB_REC;                     // 1,024

__global__ void sentinel_kernel(float* out, float v) { out[0] = v; }

// ---------------------------------------------------------------------------
// Dale weights (exact f32 sign*abs): f32 into d_ws for the sim + d_out copy.
// ---------------------------------------------------------------------------
__global__ void weights_kernel(const float* __restrict__ w_rec,
                               const float* __restrict__ w_out,
                               const float* __restrict__ w_ff,
                               const float* __restrict__ d_sign,
                               float* __restrict__ f_wrecd,
                               float* __restrict__ f_woutd,
                               float* __restrict__ o_wrecd,
                               float* __restrict__ o_woutd,
                               float* __restrict__ o_wff) {
  int idx = blockIdx.x * blockDim.x + threadIdx.x;
  if (idx < NB_REC * NB_REC) {
    int i = idx >> 10;
    float v = d_sign[i] * fabsf(w_rec[idx]);
    f_wrecd[idx] = v;
    o_wrecd[idx] = v;
    return;
  }
  int idx2 = idx - NB_REC * NB_REC;
  if (idx2 < NB_REC * NB_OUT) {
    int i = idx2 >> 6;
    float v = d_sign[i] * fabsf(w_out[idx2]);
    f_woutd[idx2] = v;
    o_woutd[idx2] = v;
    return;
  }
  int idx3 = idx2 - NB_REC * NB_OUT;
  if (idx3 < NB_IN * NB_REC) {
    o_wff[idx3] = w_ff[idx3];
  }
}

// ---------------------------------------------------------------------------
// in_ff = inputs @ w_ff emulating np.einsum: serial c-ascending f32 chain,
// separate mul/add roundings (no FMA). Unchanged from passing r7/r8.
// ---------------------------------------------------------------------------
__global__ __launch_bounds__(256)
void inff_einsum(const float* __restrict__ A,    // [rows,256]
                 const float* __restrict__ Bw,   // [256,1024]
                 float* __restrict__ C,          // [rows,1024]
                 int rows) {
  const int r0 = blockIdx.x * 8;
  const int d  = blockIdx.y * 256 + threadIdx.x;

  __shared__ float a_s[8][NB_IN];
  for (int e = threadIdx.x; e < 8 * NB_IN; e += 256) {
    int rr = e >> 8, cc = e & 255;
    a_s[rr][cc] = (r0 + rr < rows) ? A[(size_t)(r0 + rr) * NB_IN + cc] : 0.0f;
  }
  __syncthreads();

  float acc[8] = {0.f, 0.f, 0.f, 0.f, 0.f, 0.f, 0.f, 0.f};
  for (int c = 0; c < NB_IN; ++c) {
    const float w = Bw[(size_t)c * NB_REC + d];
#pragma unroll
    for (int rr = 0; rr < 8; ++rr)
      acc[rr] = __fadd_rn(acc[rr], __fmul_rn(a_s[rr][c], w));  // no FMA
  }
#pragma unroll
  for (int rr = 0; rr < 8; ++rr)
    if (r0 + rr < rows) C[(size_t)(r0 + rr) * NB_REC + d] = acc[rr];
}

// ---------------------------------------------------------------------------
// 299-step recurrence. 512 threads/block; thread owns neurons 2*tid, 2*tid+1.
// Per step: 2 ballots -> lane0 bit-interleaves into ascending mask words;
// B1; lanes 0-31 build ascending sidx (shfl prefix scan); B2; all threads
// gather their float2 column pair with grouped double-buffered loads.
// Serial ascending f32 add chain per column (pads add exact +0.0f).
// inff/noise prefetched one step ahead. 2 barriers/step.
// ---------------------------------------------------------------------------
__global__ __launch_bounds__(512, 1)
void rnn_kernel(const float* __restrict__ inff,    // [cb,300,1024]
                const float* __restrict__ noise,   // (pre-offset)
                const float* __restrict__ w_rec_d, // f32, ws
                float* __restrict__ spk_rec) {     // (pre-offset)
  const int b = blockIdx.x;
  const int tid = threadIdx.x;   // 0..511
  const int lane = tid & 63;
  const int wv = tid >> 6;       // wave 0..7

  __shared__ unsigned long long s_mask64[16];  // 32 u32 words, ascending bits
  __shared__ uint4 sidx4_s[132];               // 1056 u16 (pad for over-read)
  __shared__ int s_cnt;
  unsigned short* sidx = (unsigned short*)sidx4_s;
  const uint4* sidx4 = (const uint4*)sidx4_s;
  const unsigned* s_mask = (const unsigned*)s_mask64;

  float syn0 = 0.f, syn1 = 0.f, mem0 = 0.f, mem1 = 0.f;
  int r1_0 = 0, r1_1 = 0, r2_0 = 0, r2_1 = 0;

  {
    const float2 z = {0.f, 0.f};
    *reinterpret_cast<float2*>(&spk_rec[((size_t)b * NB_STEPS) * NB_REC + 2 * tid]) = z;
  }

  const float* wc = w_rec_d + 2 * tid;   // column pair, row stride 1024

  // prefetch t=0 inputs
  float2 inf2 = *reinterpret_cast<const float2*>(
      &inff[((size_t)b * NB_STEPS) * NB_REC + 2 * tid]);
  float2 nz2 = *reinterpret_cast<const float2*>(
      &noise[((size_t)b * NB_STEPS) * NB_REC + 2 * tid]);

  for (int t = 0; t < TSTEPS; ++t) {
    const size_t row = (size_t)b * NB_STEPS + t;

    const float me0 = (r1_0 | r2_0) ? 0.0f : mem0;
    const float me1 = (r1_1 | r2_1) ? 0.0f : mem1;
    const int sp0 = (__fsub_rn(me0, 1.0f) > 0.0f) ? 1 : 0;
    const int sp1 = (__fsub_rn(me1, 1.0f) > 0.0f) ? 1 : 0;

    const unsigned long long bl0 = __ballot(sp0);
    const unsigned long long bl1 = __ballot(sp1);
    if (lane == 0) {
      // interleave: neuron 128*wv + 2l + c <-> bit l of ballot c
      auto spread = [](unsigned v) -> unsigned long long {
        unsigned long long x = v;
        x = (x | (x << 16)) & 0x0000FFFF0000FFFFull;
        x = (x | (x << 8))  & 0x00FF00FF00FF00FFull;
        x = (x | (x << 4))  & 0x0F0F0F0F0F0F0F0Full;
        x = (x | (x << 2))  & 0x3333333333333333ull;
        x = (x | (x << 1))  & 0x5555555555555555ull;
        return x;
      };
      s_mask64[2 * wv] =
          spread((unsigned)bl0) | (spread((unsigned)bl1) << 1);
      s_mask64[2 * wv + 1] =
          spread((unsigned)(bl0 >> 32)) | (spread((unsigned)(bl1 >> 32)) << 1);
    }
    __syncthreads();  // (B1) mask words complete

    // lanes 0-31 of wave 0: deterministic ascending compaction
    if (tid < 32) {
      const unsigned m0 = s_mask[tid];
      const int pc = __popc(m0);
      int x = pc;
#pragma unroll
      for (int d = 1; d < 32; d <<= 1) {
        int y = __shfl_up(x, (unsigned)d, 64);
        if (tid >= d) x += y;
      }
      int base = x - pc;  // exclusive prefix
      unsigned m = m0;
      while (m) {
        sidx[base++] = (unsigned short)((tid << 5) + __builtin_ctz(m));
        m &= m - 1;
      }
      if (tid == 31) s_cnt = x;
    }
    __syncthreads();  // (B2) sidx/s_cnt ready

    const int S = s_cnt;

    // prefetch next step's inputs; latency hides under the gather
    const float2 inf2n = *reinterpret_cast<const float2*>(
        &inff[(row + 1) * NB_REC + 2 * tid]);
    const float2 nz2n = *reinterpret_cast<const float2*>(
        &noise[(row + 1) * NB_REC + 2 * tid]);

    // grouped, double-buffered float2 gather; serial ascending add chains
    auto grp_load = [&](int k0, float2* buf) {
      const uint4 pk = sidx4[k0 >> 3];
      const unsigned e[8] = {pk.x & 0xffffu, pk.x >> 16,
                             pk.y & 0xffffu, pk.y >> 16,
                             pk.z & 0xffffu, pk.z >> 16,
                             pk.w & 0xffffu, pk.w >> 16};
#pragma unroll
      for (int q = 0; q < 8; ++q) {
        const bool v = (k0 + q) < S;
        const float2 ld = *reinterpret_cast<const float2*>(
            &wc[(size_t)(v ? e[q] : 0u) << 10]);
        buf[q].x = v ? ld.x : 0.0f;   // pad adds exact +0.0f
        buf[q].y = v ? ld.y : 0.0f;
      }
    };

    float a0 = 0.0f, a1 = 0.0f;
    float2 bufA[8], bufB[8];
    grp_load(0, bufA);
    for (int k0 = 0; k0 < S; k0 += 16) {
      grp_load(k0 + 8, bufB);
#pragma unroll
      for (int q = 0; q < 8; ++q) {
        a0 = __fadd_rn(a0, bufA[q].x);
        a1 = __fadd_rn(a1, bufA[q].y);
      }
      grp_load(k0 + 16, bufA);
#pragma unroll
      for (int q = 0; q < 8; ++q) {
        a0 = __fadd_rn(a0, bufB[q].x);
        a1 = __fadd_rn(a1, bufB[q].y);
      }
    }

    // reference order, separate roundings, no FMA
    const float ns0 =
        __fadd_rn(__fadd_rn(__fadd_rn(__fmul_rn(ALPHA_F, syn0), a0), inf2.x), nz2.x);
    const float ns1 =
        __fadd_rn(__fadd_rn(__fadd_rn(__fmul_rn(ALPHA_F, syn1), a1), inf2.y), nz2.y);
    const float nm0 =
        __fsub_rn(__fadd_rn(__fmul_rn(BETA_F, me0), syn0), (float)sp0);
    const float nm1 =
        __fsub_rn(__fadd_rn(__fmul_rn(BETA_F, me1), syn1), (float)sp1);

    const float2 spw = {(float)sp0, (float)sp1};
    *reinterpret_cast<float2*>(&spk_rec[(row + 1) * NB_REC + 2 * tid]) = spw;

    syn0 = ns0; syn1 = ns1;
    mem0 = nm0; mem1 = nm1;
    r2_0 = r1_0; r2_1 = r1_1;
    r1_0 = sp0; r1_1 = sp1;
    inf2 = inf2n; nz2 = nz2n;
    // next iteration's B1 protects s_mask64/sidx from premature overwrite
  }
}

// ---------------------------------------------------------------------------
// out_rec[r,:] = spk_rec[r,:] @ w_out_d for ALL 38400 rows. Unchanged (r8).
// ---------------------------------------------------------------------------
__global__ __launch_bounds__(256)
void h2_kernel(const float* __restrict__ spk_rec,  // [38400,1024]
               const float* __restrict__ w_out_d,  // [1024,64] f32, ws
               float* __restrict__ out_rec,        // [38400,64]
               int nrows) {
  const int r = blockIdx.x * 4 + (threadIdx.x >> 6);
  const int lane = threadIdx.x & 63;
  if (r >= nrows) return;

  const float* spk = spk_rec + (size_t)r * NB_REC;
  const float* wo  = w_out_d + lane;   // column `lane`, row stride 64

  unsigned long long mw[16];
#pragma unroll
  for (int c = 0; c < 16; ++c)
    mw[c] = __ballot(spk[c * 64 + lane] != 0.0f);

  float acc = 0.0f;
#pragma unroll
  for (int c = 0; c < 16; ++c) {
    unsigned long long m = mw[c];
    while (m) {                     // uniform across the wave
      float w[8];
#pragma unroll
      for (int q = 0; q < 8; ++q) {
        const bool v = (m != 0ull);
        const int idx = v ? __builtin_ctzll(m) : 0;
        m &= m - 1ull;
        const float ld = wo[(size_t)(v ? (c * 64 + idx) : 0) << 6];
        w[q] = v ? ld : 0.0f;
      }
#pragma unroll
      for (int q = 0; q < 8; ++q) acc = __fadd_rn(acc, w[q]);
    }
  }
  out_rec[(size_t)r * NB_OUT + lane] = acc;
}

// ---------------------------------------------------------------------------
extern "C" void kernel_launch(void* const* d_in, const int* in_sizes, int n_in,
                              void* d_out, int out_size, void* d_ws, size_t ws_size,
                              hipStream_t stream) {
  const float *inputs = nullptr, *noise = nullptr, *w_ff = nullptr,
              *w_rec = nullptr, *w_out = nullptr, *d_sign = nullptr;
  for (int i = 0; i < n_in; ++i) {
    switch (in_sizes[i]) {
      case SZ_INPUTS: inputs = (const float*)d_in[i]; break;
      case SZ_NOISE:  noise  = (const float*)d_in[i]; break;
      case SZ_WFF:    w_ff   = (const float*)d_in[i]; break;
      case SZ_WREC:   w_rec  = (const float*)d_in[i]; break;
      case SZ_WOUT:   w_out  = (const float*)d_in[i]; break;
      case SZ_DSIGN:  d_sign = (const float*)d_in[i]; break;
      default: break;
    }
  }

  float* out = (float*)d_out;
  const size_t W_BYTES = (size_t)(SZ_WREC + SZ_WOUT) * sizeof(float);

  float sentinel = 0.0f;
  if (!inputs || !noise || !w_ff || !w_rec || !w_out || !d_sign) {
    sentinel = 300.0f;
  } else if (out_size != OUT_TOTAL) {
    sentinel = 700.0f;
  }

  int CB = 0;
  if (sentinel == 0.0f) {
    const int cands[4] = {128, 64, 32, 16};
    for (int i = 0; i < 4; ++i) {
      size_t need = W_BYTES + (size_t)cands[i] * NB_STEPS * NB_REC * sizeof(float);
      if (need <= ws_size) { CB = cands[i]; break; }
    }
    if (CB == 0) sentinel = 500.0f + (float)(ws_size >> 20);
  }

  if (sentinel != 0.0f) {
    sentinel_kernel<<<1, 1, 0, stream>>>(out, sentinel);
    return;
  }

  float* out_rec = out + OUT_REC_OFF;
  float* spk_rec = out + SPK_REC_OFF;
  float* o_wrecd = out + WRECD_OFF;
  float* o_woutd = out + WOUTD_OFF;
  float* o_wff   = out + WFF_OFF;

  float* f_wrecd = (float*)d_ws;
  float* f_woutd = f_wrecd + SZ_WREC;
  float* inff    = f_woutd + SZ_WOUT;

  {
    int total = NB_REC * NB_REC + NB_REC * NB_OUT + NB_IN * NB_REC;
    int blocks = (total + 255) / 256;
    weights_kernel<<<blocks, 256, 0, stream>>>(w_rec, w_out, w_ff, d_sign,
                                               f_wrecd, f_woutd,
                                               o_wrecd, o_woutd, o_wff);
  }

  for (int b0 = 0; b0 < BATCH; b0 += CB) {
    const int cb = (BATCH - b0 < CB) ? (BATCH - b0) : CB;
    const int rows = cb * NB_STEPS;
    const float* Aptr = inputs + (size_t)b0 * NB_STEPS * NB_IN;
    const float* Nptr = noise + (size_t)b0 * NB_STEPS * NB_REC;
    float* srec = spk_rec + (size_t)b0 * NB_STEPS * NB_REC;

    dim3 ggrid((rows + 7) / 8, NB_REC / 256);
    inff_einsum<<<ggrid, 256, 0, stream>>>(Aptr, w_ff, inff, rows);
    rnn_kernel<<<cb, 512, 0, stream>>>(inff, Nptr, f_wrecd, srec);
  }

  {
    const int nrows = BATCH * NB_STEPS;  // 38400
    h2_kernel<<<(nrows + 3) / 4, 256, 0, stream>>>(spk_rec, f_woutd,
                                                   out_rec, nrows);
  }
}

// Round 10
// 2218.479 us; speedup vs baseline: 2.1140x; 2.1140x over previous
//
#include <hip/hip_runtime.h>

// ---------------------------------------------------------------------------
// SpikeRNN — r10: r8 structure (1024 thr / 16 waves, known 2620us) plus:
//  * ONE barrier/step (ping-pong masks + per-wave private compaction)
//  * compaction in every wave (was wave0-only, 15 waves idling)
//  * zero-row padding (w staged as [1025,1024], row 1024 = 0; pad idx = 1024)
//    -> inner loop is pure load+fadd, no selects/branches
//  * group-16 double-buffered gather (32 loads in flight/thread)
//  * inff/noise prefetched before the barrier
// Numerics bit-identical to passing r7/r8: ascending serial f32 chains, no FMA.
// ---------------------------------------------------------------------------

constexpr int NB_IN  = 256;
constexpr int NB_REC = 1024;
constexpr int NB_OUT = 64;
constexpr int BATCH  = 128;
constexpr int NB_STEPS = 300;
constexpr int TSTEPS = NB_STEPS - 1;

constexpr float ALPHA_F = (float)0.8187307530779818;  // f32(exp(-0.2))
constexpr float BETA_F  = (float)0.9048374180359595;  // f32(exp(-0.1))

// d_out element offsets (f32 elements)
constexpr size_t OUT_REC_OFF = 0;
constexpr size_t SPK_REC_OFF = (size_t)BATCH * NB_STEPS * NB_OUT;
constexpr size_t WRECD_OFF   = SPK_REC_OFF + (size_t)BATCH * NB_STEPS * NB_REC;
constexpr size_t WOUTD_OFF   = WRECD_OFF + (size_t)NB_REC * NB_REC;
constexpr size_t WFF_OFF     = WOUTD_OFF + (size_t)NB_REC * NB_OUT;
constexpr int    OUT_TOTAL   = 43155456;

constexpr int SZ_INPUTS = BATCH * NB_STEPS * NB_IN;   // 9,830,400
constexpr int SZ_NOISE  = BATCH * NB_STEPS * NB_REC;  // 39,321,600
constexpr int SZ_WFF    = NB_IN * NB_REC;             // 262,144
constexpr int SZ_WREC   = NB_REC * NB_REC;            // 1,048,576
constexpr int SZ_WOUT   = NB_REC * NB_OUT;            // 65,536
constexpr int SZ_DSIGN  = NB_REC;                     // 1,024

constexpr int WREC_ROWS = NB_REC + 1;                 // +1 zero row for padding

__global__ void sentinel_kernel(float* out, float v) { out[0] = v; }

// ---------------------------------------------------------------------------
// Dale weights: f32 [1025,1024] wrec copy (row 1024 zeroed) + wout copy into
// d_ws; f32 copies of wrec/wout/wff into d_out (scored outputs).
// ---------------------------------------------------------------------------
__global__ void weights_kernel(const float* __restrict__ w_rec,
                               const float* __restrict__ w_out,
                               const float* __restrict__ w_ff,
                               const float* __restrict__ d_sign,
                               float* __restrict__ f_wrecd,   // [1025,1024] ws
                               float* __restrict__ f_woutd,   // [1024,64] ws
                               float* __restrict__ o_wrecd,
                               float* __restrict__ o_woutd,
                               float* __restrict__ o_wff) {
  int idx = blockIdx.x * blockDim.x + threadIdx.x;
  if (idx < NB_REC * NB_REC) {
    int i = idx >> 10;
    float v = d_sign[i] * fabsf(w_rec[idx]);
    f_wrecd[idx] = v;
    o_wrecd[idx] = v;
    return;
  }
  int idx2 = idx - NB_REC * NB_REC;
  if (idx2 < NB_REC * NB_OUT) {
    int i = idx2 >> 6;
    float v = d_sign[i] * fabsf(w_out[idx2]);
    f_woutd[idx2] = v;
    o_woutd[idx2] = v;
    return;
  }
  int idx3 = idx2 - NB_REC * NB_OUT;
  if (idx3 < NB_IN * NB_REC) {
    o_wff[idx3] = w_ff[idx3];
    return;
  }
  int idx4 = idx3 - NB_IN * NB_REC;
  if (idx4 < NB_REC) {
    f_wrecd[(size_t)NB_REC * NB_REC + idx4] = 0.0f;   // zero row 1024
  }
}

// ---------------------------------------------------------------------------
// in_ff = inputs @ w_ff emulating np.einsum: serial c-ascending f32 chain,
// separate mul/add roundings (no FMA). Unchanged from passing r7/r8.
// ---------------------------------------------------------------------------
__global__ __launch_bounds__(256)
void inff_einsum(const float* __restrict__ A,    // [rows,256]
                 const float* __restrict__ Bw,   // [256,1024]
                 float* __restrict__ C,          // [rows,1024]
                 int rows) {
  const int r0 = blockIdx.x * 8;
  const int d  = blockIdx.y * 256 + threadIdx.x;

  __shared__ float a_s[8][NB_IN];
  for (int e = threadIdx.x; e < 8 * NB_IN; e += 256) {
    int rr = e >> 8, cc = e & 255;
    a_s[rr][cc] = (r0 + rr < rows) ? A[(size_t)(r0 + rr) * NB_IN + cc] : 0.0f;
  }
  __syncthreads();

  float acc[8] = {0.f, 0.f, 0.f, 0.f, 0.f, 0.f, 0.f, 0.f};
  for (int c = 0; c < NB_IN; ++c) {
    const float w = Bw[(size_t)c * NB_REC + d];
#pragma unroll
    for (int rr = 0; rr < 8; ++rr)
      acc[rr] = __fadd_rn(acc[rr], __fmul_rn(a_s[rr][c], w));  // no FMA
  }
#pragma unroll
  for (int rr = 0; rr < 8; ++rr)
    if (r0 + rr < rows) C[(size_t)(r0 + rr) * NB_REC + d] = acc[rr];
}

// ---------------------------------------------------------------------------
// 299-step recurrence. 1024 threads (16 waves), thread j = neuron/column j.
// Per step: ballot -> s_mask[parity]; prefetch next inputs; ONE barrier;
// every wave privately compacts masks into its own ascending sidx (+48 pad
// entries = 1024 -> zero weight row); group-16 double-buffered gather with
// pure load+serial-fadd chain. All cross-wave R/W separated by the barrier
// (masks ping-ponged); sidx is wave-private (in-order within a wave).
// ---------------------------------------------------------------------------
__global__ __launch_bounds__(1024, 1)
void rnn_kernel(const float* __restrict__ inff,    // [cb,300,1024]
                const float* __restrict__ noise,   // (pre-offset)
                const float* __restrict__ w_rec_d, // [1025,1024] f32, ws
                float* __restrict__ spk_rec) {     // (pre-offset)
  const int b = blockIdx.x;
  const int j = threadIdx.x;
  const int lane = j & 63;
  const int wv = j >> 6;       // wave 0..15

  __shared__ unsigned s_mask[2][32];
  __shared__ uint4 sidx4_s[16][136];   // per-wave: 1088 u16 entries

  unsigned short* sidxw = (unsigned short*)sidx4_s[wv];
  const uint4* sidx4w = (const uint4*)sidx4_s[wv];

  float syn = 0.0f, mem = 0.0f;
  int rst1 = 0, rst2 = 0;

  spk_rec[((size_t)b * NB_STEPS) * NB_REC + j] = 0.0f;

  const float* wc = w_rec_d + j;   // column j, row stride 1024 floats

  // prefetch t=0 inputs
  float inf = inff[((size_t)b * NB_STEPS) * NB_REC + j];
  float nz  = noise[((size_t)b * NB_STEPS) * NB_REC + j];

  for (int t = 0; t < TSTEPS; ++t) {
    const int p = t & 1;
    const size_t row = (size_t)b * NB_STEPS + t;

    const float mem_eff = (rst1 | rst2) ? 0.0f : mem;
    const int spike = (__fsub_rn(mem_eff, 1.0f) > 0.0f) ? 1 : 0;

    const unsigned long long msk = __ballot(spike);
    if (lane == 0) {
      s_mask[p][2 * wv]     = (unsigned)msk;
      s_mask[p][2 * wv + 1] = (unsigned)(msk >> 32);
    }

    // prefetch next step's inputs; latency hides under barrier+compaction+gather
    const float infn = inff[(row + 1) * NB_REC + j];
    const float nzn  = noise[(row + 1) * NB_REC + j];

    __syncthreads();  // (B) masks complete; prev-iter sidx reads long done

    // per-wave private compaction (ascending): lanes 0..31 own mask words
    const unsigned m0 = (lane < 32) ? s_mask[p][lane] : 0u;
    const int pc = __popc(m0);
    int x = pc;
#pragma unroll
    for (int d = 1; d < 64; d <<= 1) {
      int y = __shfl_up(x, (unsigned)d, 64);
      if (lane >= d) x += y;
    }
    int base = x - pc;           // exclusive prefix
    unsigned m = m0;
    while (m) {
      const int bit = __builtin_ctz(m);
      m &= m - 1;
      sidxw[base++] = (unsigned short)((lane << 5) + bit);
    }
    const int S = __shfl(x, 63); // total spike count
    if (lane < 48) sidxw[S + lane] = (unsigned short)NB_REC;  // pad -> zero row

    // group-16 double-buffered gather; strictly serial ascending f32 chain
    auto load16 = [&](int k, float* buf) {
      const uint4 p0 = sidx4w[(k >> 3) + 0];
      const uint4 p1 = sidx4w[(k >> 3) + 1];
      const unsigned e[16] = {
          p0.x & 0xffffu, p0.x >> 16, p0.y & 0xffffu, p0.y >> 16,
          p0.z & 0xffffu, p0.z >> 16, p0.w & 0xffffu, p0.w >> 16,
          p1.x & 0xffffu, p1.x >> 16, p1.y & 0xffffu, p1.y >> 16,
          p1.z & 0xffffu, p1.z >> 16, p1.w & 0xffffu, p1.w >> 16};
#pragma unroll
      for (int q = 0; q < 16; ++q)
        buf[q] = wc[(size_t)e[q] << 10];
    };

    float acc = 0.0f;
    float bufA[16], bufB[16];
    load16(0, bufA);
    for (int k0 = 0; k0 < S; k0 += 32) {
      load16(k0 + 16, bufB);
#pragma unroll
      for (int q = 0; q < 16; ++q) acc = __fadd_rn(acc, bufA[q]);
      load16(k0 + 32, bufA);
#pragma unroll
      for (int q = 0; q < 16; ++q) acc = __fadd_rn(acc, bufB[q]);
    }

    // reference order, separate roundings, no FMA
    const float new_syn =
        __fadd_rn(__fadd_rn(__fadd_rn(__fmul_rn(ALPHA_F, syn), acc), inf), nz);
    const float new_mem =
        __fsub_rn(__fadd_rn(__fmul_rn(BETA_F, mem_eff), syn), (float)spike);

    spk_rec[(row + 1) * NB_REC + j] = (float)spike;

    syn = new_syn;
    mem = new_mem;
    rst2 = rst1;
    rst1 = spike;
    inf = infn;
    nz = nzn;
  }
}

// ---------------------------------------------------------------------------
// out_rec[r,:] = spk_rec[r,:] @ w_out_d for ALL 38400 rows. Unchanged (r8).
// ---------------------------------------------------------------------------
__global__ __launch_bounds__(256)
void h2_kernel(const float* __restrict__ spk_rec,  // [38400,1024]
               const float* __restrict__ w_out_d,  // [1024,64] f32, ws
               float* __restrict__ out_rec,        // [38400,64]
               int nrows) {
  const int r = blockIdx.x * 4 + (threadIdx.x >> 6);
  const int lane = threadIdx.x & 63;
  if (r >= nrows) return;

  const float* spk = spk_rec + (size_t)r * NB_REC;
  const float* wo  = w_out_d + lane;   // column `lane`, row stride 64

  unsigned long long mw[16];
#pragma unroll
  for (int c = 0; c < 16; ++c)
    mw[c] = __ballot(spk[c * 64 + lane] != 0.0f);

  float acc = 0.0f;
#pragma unroll
  for (int c = 0; c < 16; ++c) {
    unsigned long long m = mw[c];
    while (m) {                     // uniform across the wave
      float w[8];
#pragma unroll
      for (int q = 0; q < 8; ++q) {
        const bool v = (m != 0ull);
        const int idx = v ? __builtin_ctzll(m) : 0;
        m &= m - 1ull;
        const float ld = wo[(size_t)(v ? (c * 64 + idx) : 0) << 6];
        w[q] = v ? ld : 0.0f;
      }
#pragma unroll
      for (int q = 0; q < 8; ++q) acc = __fadd_rn(acc, w[q]);
    }
  }
  out_rec[(size_t)r * NB_OUT + lane] = acc;
}

// ---------------------------------------------------------------------------
extern "C" void kernel_launch(void* const* d_in, const int* in_sizes, int n_in,
                              void* d_out, int out_size, void* d_ws, size_t ws_size,
                              hipStream_t stream) {
  const float *inputs = nullptr, *noise = nullptr, *w_ff = nullptr,
              *w_rec = nullptr, *w_out = nullptr, *d_sign = nullptr;
  for (int i = 0; i < n_in; ++i) {
    switch (in_sizes[i]) {
      case SZ_INPUTS: inputs = (const float*)d_in[i]; break;
      case SZ_NOISE:  noise  = (const float*)d_in[i]; break;
      case SZ_WFF:    w_ff   = (const float*)d_in[i]; break;
      case SZ_WREC:   w_rec  = (const float*)d_in[i]; break;
      case SZ_WOUT:   w_out  = (const float*)d_in[i]; break;
      case SZ_DSIGN:  d_sign = (const float*)d_in[i]; break;
      default: break;
    }
  }

  float* out = (float*)d_out;
  const size_t W_ELEMS = (size_t)WREC_ROWS * NB_REC + SZ_WOUT;  // wrec+zero row+wout
  const size_t W_BYTES = W_ELEMS * sizeof(float);

  float sentinel = 0.0f;
  if (!inputs || !noise || !w_ff || !w_rec || !w_out || !d_sign) {
    sentinel = 300.0f;
  } else if (out_size != OUT_TOTAL) {
    sentinel = 700.0f;
  }

  int CB = 0;
  if (sentinel == 0.0f) {
    const int cands[4] = {128, 64, 32, 16};
    for (int i = 0; i < 4; ++i) {
      size_t need = W_BYTES + (size_t)cands[i] * NB_STEPS * NB_REC * sizeof(float);
      if (need <= ws_size) { CB = cands[i]; break; }
    }
    if (CB == 0) sentinel = 500.0f + (float)(ws_size >> 20);
  }

  if (sentinel != 0.0f) {
    sentinel_kernel<<<1, 1, 0, stream>>>(out, sentinel);
    return;
  }

  float* out_rec = out + OUT_REC_OFF;
  float* spk_rec = out + SPK_REC_OFF;
  float* o_wrecd = out + WRECD_OFF;
  float* o_woutd = out + WOUTD_OFF;
  float* o_wff   = out + WFF_OFF;

  float* f_wrecd = (float*)d_ws;                            // [1025,1024]
  float* f_woutd = f_wrecd + (size_t)WREC_ROWS * NB_REC;    // [1024,64]
  float* inff    = f_woutd + SZ_WOUT;

  {
    int total = NB_REC * NB_REC + NB_REC * NB_OUT + NB_IN * NB_REC + NB_REC;
    int blocks = (total + 255) / 256;
    weights_kernel<<<blocks, 256, 0, stream>>>(w_rec, w_out, w_ff, d_sign,
                                               f_wrecd, f_woutd,
                                               o_wrecd, o_woutd, o_wff);
  }

  for (int b0 = 0; b0 < BATCH; b0 += CB) {
    const int cb = (BATCH - b0 < CB) ? (BATCH - b0) : CB;
    const int rows = cb * NB_STEPS;
    const float* Aptr = inputs + (size_t)b0 * NB_STEPS * NB_IN;
    const float* Nptr = noise + (size_t)b0 * NB_STEPS * NB_REC;
    float* srec = spk_rec + (size_t)b0 * NB_STEPS * NB_REC;

    dim3 ggrid((rows + 7) / 8, NB_REC / 256);
    inff_einsum<<<ggrid, 256, 0, stream>>>(Aptr, w_ff, inff, rows);
    rnn_kernel<<<cb, 1024, 0, stream>>>(inff, Nptr, f_wrecd, srec);
  }

  {
    const int nrows = BATCH * NB_STEPS;  // 38400
    h2_kernel<<<(nrows + 3) / 4, 256, 0, stream>>>(spk_rec, f_woutd,
                                                   out_rec, nrows);
  }
}